// Round 1
// 846.572 us; speedup vs baseline: 1.0402x; 1.0402x over previous
//
#include <hip/hip_runtime.h>
#include <stdint.h>

#define LQ 2048
#define EDIM 1024
#define HN 8
#define DH 128
#define BATCH 4
#define SCALE_LOG2E 0.12753785051263942f  // (1/sqrt(128)) * log2(e)

typedef short bf16x8 __attribute__((ext_vector_type(8)));
typedef float f32x4 __attribute__((ext_vector_type(4)));
typedef unsigned short u16;
typedef unsigned short u16x4 __attribute__((ext_vector_type(4)));

__device__ __forceinline__ u16 f2bf(float f) {
  union { float f; uint32_t u; } c; c.f = f;
  uint32_t u = c.u;
  return (u16)((u + 0x7fffu + ((u >> 16) & 1u)) >> 16);
}

__device__ __forceinline__ void async16(const void* g, void* l) {
  __builtin_amdgcn_global_load_lds((const __attribute__((address_space(1))) void*)g,
                                   (__attribute__((address_space(3))) void*)l, 16, 0, 0);
}

// LDS byte address for inline-asm DS ops
__device__ __forceinline__ uint32_t lds_b(const u16* p) {
  return (uint32_t)(uintptr_t)(__attribute__((address_space(3))) const u16*)p;
}
// 4x ds_read_b128 + single lgkm drain. Outputs MUST be early-clobber ("=&v"):
// the first ds_read writes its dest before later reads consume their address
// regs; without & the allocator may overlap them -> corrupted fragments (R6 bug).
__device__ __forceinline__ void ldsr4(bf16x8& d0, bf16x8& d1, bf16x8& d2, bf16x8& d3,
                                      uint32_t a0, uint32_t a1, uint32_t a2, uint32_t a3) {
  asm volatile("ds_read_b128 %0, %4\n\t"
               "ds_read_b128 %1, %5\n\t"
               "ds_read_b128 %2, %6\n\t"
               "ds_read_b128 %3, %7\n\t"
               "s_waitcnt lgkmcnt(0)"
               : "=&v"(d0), "=&v"(d1), "=&v"(d2), "=&v"(d3)
               : "v"(a0), "v"(a1), "v"(a2), "v"(a3));
}
// v_cvt_pk_bf16_f32: two f32 -> packed 2xbf16 in one u32 (lo <- first arg).
// No builtin on gfx950; the P->bf16 conversion NEEDS the packed form for the
// in-register A-fragment build, so inline asm is the right tool here.
__device__ __forceinline__ uint32_t cvtpk(float lo, float hi) {
  uint32_t r;
  asm("v_cvt_pk_bf16_f32 %0, %1, %2" : "=v"(r) : "v"(lo), "v"(hi));
  return r;
}
// 8x ds_bpermute + single lgkm drain: d{0..3} = {s0,s1}@al, {s0,s1}@ah ; d{4..7} same for s2,s3.
__device__ __forceinline__ void bperm8(uint32_t& d0, uint32_t& d1, uint32_t& d2, uint32_t& d3,
                                       uint32_t& d4, uint32_t& d5, uint32_t& d6, uint32_t& d7,
                                       uint32_t al, uint32_t ah,
                                       uint32_t s0, uint32_t s1, uint32_t s2, uint32_t s3) {
  asm volatile("ds_bpermute_b32 %0, %8, %10\n\t"
               "ds_bpermute_b32 %1, %8, %11\n\t"
               "ds_bpermute_b32 %2, %9, %10\n\t"
               "ds_bpermute_b32 %3, %9, %11\n\t"
               "ds_bpermute_b32 %4, %8, %12\n\t"
               "ds_bpermute_b32 %5, %8, %13\n\t"
               "ds_bpermute_b32 %6, %9, %12\n\t"
               "ds_bpermute_b32 %7, %9, %13\n\t"
               "s_waitcnt lgkmcnt(0)"
               : "=&v"(d0), "=&v"(d1), "=&v"(d2), "=&v"(d3),
                 "=&v"(d4), "=&v"(d5), "=&v"(d6), "=&v"(d7)
               : "v"(al), "v"(ah), "v"(s0), "v"(s1), "v"(s2), "v"(s3));
}

// ---------------- fused prep: cvt inputs + transpose weights ----------------
// (mask tile scan moved into qkv_gemm z=3 plane: it is pure HBM and overlaps
//  the compute-bound GEMM for free instead of serializing here)
__global__ __launch_bounds__(256) void prep_kernel(const float* __restrict__ qIn, const float* __restrict__ kvIn,
                                                   const float* __restrict__ w0, const float* __restrict__ w1,
                                                   const float* __restrict__ w2, const float* __restrict__ w3,
                                                   u16* __restrict__ oq, u16* __restrict__ okv,
                                                   u16* __restrict__ o0, u16* __restrict__ o1,
                                                   u16* __restrict__ o2, u16* __restrict__ o3) {
  __shared__ float tile[32][33];
  const int bid = blockIdx.x;
  const int t = threadIdx.x;
  if (bid < 16384) {
    const float* in = (bid >= 8192) ? kvIn : qIn;
    u16* out = (bid >= 8192) ? okv : oq;
    size_t i = (size_t)(bid & 8191) * 256 + t;
    float4 v = ((const float4*)in)[i];
    u16x4 o;
    o.x = f2bf(v.x); o.y = f2bf(v.y); o.z = f2bf(v.z); o.w = f2bf(v.w);
    ((u16x4*)out)[i] = o;
  } else {
    const int idx = bid - 16384;
    const int z = idx >> 10;
    const int rem = idx & 1023;
    const float* in; u16* out;
    switch (z) {
      case 0: in = w0; out = o0; break;
      case 1: in = w1; out = o1; break;
      case 2: in = w2; out = o2; break;
      default: in = w3; out = o3; break;
    }
    const int tx = t & 31, ty = t >> 5;
    const int x0 = (rem & 31) * 32;
    const int y0 = (rem >> 5) * 32;
#pragma unroll
    for (int j = 0; j < 32; j += 8)
      tile[ty + j][tx] = in[(size_t)(y0 + ty + j) * EDIM + x0 + tx];
    __syncthreads();
#pragma unroll
    for (int j = 0; j < 32; j += 8)
      out[(size_t)(x0 + ty + j) * EDIM + (y0 + tx)] = f2bf(tile[tx][ty + j]);
  }
}

// ---------------- BK=64 GEMM core (XOR-swizzled LDS, 128x128 tile) ----------------
struct GemmCore {
  template <typename EpiF>
  static __device__ __forceinline__ void run(const u16* __restrict__ A, const u16* __restrict__ Bt,
                                             int m0, int n0, u16* As, u16* Bs, EpiF epi) {
    const int tid = threadIdx.x;
    const int l = tid & 63;
    const int w = tid >> 6;
    const int wm = (w >> 1) * 64;
    const int wn = (w & 1) * 64;
    const int fm = l & 15;
    const int q4 = l >> 4;
    const int f7 = fm & 7;
    f32x4 acc[4][4] = {};
    for (int k0 = 0; k0 < EDIM; k0 += 64) {
      __syncthreads();
#pragma unroll
      for (int ii = 0; ii < 4; ++ii) {
        const int rloc = w * 32 + ii * 8 + (l >> 3);
        const int cs = (l & 7) ^ (rloc & 7);
        async16(A + (size_t)(m0 + rloc) * EDIM + k0 + cs * 8, &As[(w * 32 + ii * 8) * 64 + l * 8]);
        async16(Bt + (size_t)(n0 + rloc) * EDIM + k0 + cs * 8, &Bs[(w * 32 + ii * 8) * 64 + l * 8]);
      }
      __syncthreads();
#pragma unroll
      for (int ks = 0; ks < 2; ++ks) {
        const int coff = ((ks * 4 + q4) ^ f7) * 8;
        bf16x8 a[4], b[4];
#pragma unroll
        for (int i = 0; i < 4; ++i) a[i] = *(const bf16x8*)&As[(wm + i * 16 + fm) * 64 + coff];
#pragma unroll
        for (int j = 0; j < 4; ++j) b[j] = *(const bf16x8*)&Bs[(wn + j * 16 + fm) * 64 + coff];
#pragma unroll
        for (int i = 0; i < 4; ++i)
#pragma unroll
          for (int j = 0; j < 4; ++j)
            acc[i][j] = __builtin_amdgcn_mfma_f32_16x16x32_bf16(a[i], b[j], acc[i][j], 0, 0, 0);
      }
    }
    const int rr = q4 * 4;
#pragma unroll
    for (int i = 0; i < 4; ++i)
#pragma unroll
      for (int j = 0; j < 4; ++j)
#pragma unroll
        for (int r = 0; r < 4; ++r)
          epi(m0 + wm + i * 16 + rr + r, n0 + wn + j * 16 + fm, acc[i][j][r]);
  }
};

__global__ __launch_bounds__(256) void qkv_gemm(const u16* __restrict__ xq, const u16* __restrict__ xkv,
                                                const u16* __restrict__ WqT, const u16* __restrict__ WkT,
                                                const u16* __restrict__ WvT,
                                                u16* __restrict__ Qb, u16* __restrict__ Kb,
                                                u16* __restrict__ Vt,
                                                const unsigned char* __restrict__ mask,
                                                unsigned char* __restrict__ flags) {
  __shared__ __align__(16) u16 As[128 * 64];
  __shared__ __align__(16) u16 Bs[128 * 64];
  __shared__ int wany[4];
  const int z = blockIdx.z;
  if (z == 3) {
    // mask tile scan: 512 blocks x 16 tiles = 8192 (bh, 128x128-tile) units.
    // Memory-bound; overlaps the compute-bound GEMM planes.
    const int t = threadIdx.x;
    const int unit0 = (blockIdx.x * 8 + blockIdx.y) * 16;
#pragma unroll 1
    for (int u = 0; u < 16; ++u) {
      const int idx = unit0 + u;
      const int bh = idx >> 8;
      const int tile16 = idx & 255;
      const int qt = tile16 >> 4, kt = tile16 & 15;
      const int r = t >> 1;
      const size_t base = ((size_t)bh * LQ + qt * 128 + r) * LQ + kt * 128 + (t & 1) * 64;
      const uint4* p = (const uint4*)(mask + base);
      uint4 a = p[0], c = p[1], d = p[2], e = p[3];
      uint32_t any = a.x | a.y | a.z | a.w | c.x | c.y | c.z | c.w |
                     d.x | d.y | d.z | d.w | e.x | e.y | e.z | e.w;
      int wa = __any(any != 0);
      if ((t & 63) == 0) wany[t >> 6] = wa;
      __syncthreads();
      if (t == 0)
        flags[(size_t)bh * 256 + tile16] = (unsigned char)(wany[0] | wany[1] | wany[2] | wany[3]);
      __syncthreads();  // wany reused next unit
    }
    return;
  }
  if (z == 0) {
    GemmCore::run(xq, WqT, blockIdx.x * 128, blockIdx.y * 128, As, Bs,
                  [&](int gm, int gn, float v) { Qb[(size_t)gm * EDIM + gn] = f2bf(v); });
  } else if (z == 1) {
    GemmCore::run(xkv, WkT, blockIdx.x * 128, blockIdx.y * 128, As, Bs,
                  [&](int gm, int gn, float v) { Kb[(size_t)gm * EDIM + gn] = f2bf(v); });
  } else {
    GemmCore::run(WvT, xkv, blockIdx.y * 128, blockIdx.x * 128, As, Bs,
                  [&](int gm, int gn, float v) {
                    Vt[((size_t)(gn >> 11) * 1024 + gm) * 2048 + (gn & 2047)] = f2bf(v);
                  });
  }
}

__global__ __launch_bounds__(256) void out_gemm(const u16* __restrict__ ctx, const u16* __restrict__ WfcT,
                                                float* __restrict__ out) {
  __shared__ __align__(16) u16 As[128 * 64];
  __shared__ __align__(16) u16 Bs[128 * 64];
  GemmCore::run(ctx, WfcT, blockIdx.x * 128, blockIdx.y * 128, As, Bs,
                [&](int gm, int gn, float v) { out[(size_t)gm * EDIM + gn] = v; });
}

// ---------------- flash attention v4: swapped QK^T, in-register P ----------------
// grid (qtile=16, h=8, b=4); 4 waves x 32 q-rows. LDS 64 KB -> 2 blocks/CU.
// St = mfma(K_frag, Q_frag): A/B fragment layouts for 16x16x32 are index-identical
// (free dim = lane&15, k = (lane>>4)*8), so the SAME LDS K reads and Q registers
// serve swapped roles. St[kt][mt][r] = S[key=16kt+4q4+r][q=16mt+fm]: the q index is
// lane-local (fm), so softmax row-sum = 16 local adds + shfl_xor(16,32), and the PV
// A-fragment (P[q=fm][key=32ns+8q4+j]) is built IN REGISTER:
//   key 32ns+8q4+j lives on lane (fm, q4'=2(q4&1)+(j>>2)), reg pk[2ns+(q4>>1)][(j&3)>>1]
// -> 16 cvt_pk + 32 ds_bpermute + 16 cndmask per iter, replacing the old P-LDS
// round-trip (32 f2bf + 32 ds_write_b16 + lgkm drain + 4 ds_read_b128).
__global__ __launch_bounds__(256, 2) void attn_kernel(const u16* __restrict__ Qb, const u16* __restrict__ Kb,
                                                      const u16* __restrict__ Vt,
                                                      const unsigned char* __restrict__ mask,
                                                      const unsigned char* __restrict__ flags,
                                                      u16* __restrict__ ctx) {
  __shared__ __align__(16) u16 Ktile[2][64 * 128];   // [key][d] rows 256B = 16 chunks, XOR-swizzled
  __shared__ __align__(16) u16 Vtile[2][128 * 64];   // [d][key] rows 128B = 8 chunks, XOR-swizzled
  const int tid = threadIdx.x;
  const int l = tid & 63;
  const int w = tid >> 6;
  const int qt = blockIdx.x;
  const int h = blockIdx.y;
  const int b = blockIdx.z;
  const int fm = l & 15;
  const int q4 = l >> 4;
  const int fk = q4 * 8;
  const int f7 = fm & 7;
  const int qbase = qt * 128 + w * 32;
  const int bh = b * HN + h;

  const u16* Kbh = Kb + (size_t)b * LQ * EDIM + h * DH;
  const u16* Vth = Vt + (size_t)bh * DH * LQ;
  const size_t mbase = (size_t)bh * (size_t)LQ * LQ;

  const unsigned char* tf = flags + (size_t)bh * 256 + qt * 16;
  uint32_t fmask = 0;
#pragma unroll
  for (int i = 0; i < 16; ++i) fmask |= (tf[i] ? 1u : 0u) << i;

  // Q fragments (issued before DMA so vmcnt ordering keeps them oldest)
  bf16x8 qf[2][4];
#pragma unroll
  for (int mt = 0; mt < 2; ++mt)
#pragma unroll
    for (int ks = 0; ks < 4; ++ks)
      qf[mt][ks] = *(const bf16x8*)(Qb + (size_t)(b * LQ + qbase + mt * 16 + fm) * EDIM + h * DH + ks * 32 + fk);

  auto stageK = [&](int kt_, int buf) {
#pragma unroll
    for (int ii = 0; ii < 4; ++ii) {
      const int i = w * 4 + ii;
      const int row = i * 4 + (l >> 4);          // key row 0..63
      const int g = (l & 15) ^ (row & 7);        // global chunk fetched into slot l&15
      async16(Kbh + (size_t)(kt_ * 64 + row) * EDIM + g * 8, &Ktile[buf][i * 512 + l * 8]);
    }
  };
  auto stageV = [&](int kt_, int buf) {
#pragma unroll
    for (int ii = 0; ii < 4; ++ii) {
      const int i = w * 4 + ii;
      const int row = i * 8 + (l >> 3);          // d row 0..127
      const int g = (l & 7) ^ (row & 7);
      async16(Vth + (size_t)row * LQ + kt_ * 64 + g * 8, &Vtile[buf][i * 512 + l * 8]);
    }
  };

  stageK(0, 0);
  stageV(0, 0);

  f32x4 o[2][8] = {};
  float lsumv[2] = {0.f, 0.f};
  // bpermute byte addrs: low source lane = (fm, q4'=2(q4&1)), high = +16
  const uint32_t al = (uint32_t)((fm + 16 * (2 * (q4 & 1))) << 2);
  const uint32_t ah = al + 64u;
  const bool sel_hi = (q4 >> 1) != 0;   // kt' = 2ns + (q4>>1)

  for (int it = 0; it < 32; ++it) {
    const int cur = it & 1;
    // one barrier: (a) drains own K/V(it) DMA (issued a full iter ago -> ~free),
    // (b) all waves done reading buffers [1-cur] from iter it-1.
    __syncthreads();
    if (it + 1 < 32) { stageK(it + 1, 1 - cur); stageV(it + 1, 1 - cur); }

    const u16* KT = &Ktile[cur][0];
    const u16* VT = &Vtile[cur][0];

    // ---- St = K Q^T (swapped operands; same K frag reads as before)
    f32x4 st[4][2] = {};
#pragma unroll
    for (int ks = 0; ks < 4; ++ks) {
      const int slot = (ks * 4 + q4) ^ f7;       // chunk 4ks+q4, XOR low3
      bf16x8 kf0, kf1, kf2, kf3;
      ldsr4(kf0, kf1, kf2, kf3,
            lds_b(KT + (0 * 16 + fm) * 128 + slot * 8),
            lds_b(KT + (1 * 16 + fm) * 128 + slot * 8),
            lds_b(KT + (2 * 16 + fm) * 128 + slot * 8),
            lds_b(KT + (3 * 16 + fm) * 128 + slot * 8));
#pragma unroll
      for (int mt = 0; mt < 2; ++mt) {
        st[0][mt] = __builtin_amdgcn_mfma_f32_16x16x32_bf16(kf0, qf[mt][ks], st[0][mt], 0, 0, 0);
        st[1][mt] = __builtin_amdgcn_mfma_f32_16x16x32_bf16(kf1, qf[mt][ks], st[1][mt], 0, 0, 0);
        st[2][mt] = __builtin_amdgcn_mfma_f32_16x16x32_bf16(kf2, qf[mt][ks], st[2][mt], 0, 0, 0);
        st[3][mt] = __builtin_amdgcn_mfma_f32_16x16x32_bf16(kf3, qf[mt][ks], st[3][mt], 0, 0, 0);
      }
    }

    // ---- softmax (no max-subtraction; masked -> 0). Mask reads only if tile flagged.
    const int hasMask = (fmask >> (it >> 1)) & 1;
    uint32_t pk[2][4][2];
#pragma unroll
    for (int mt = 0; mt < 2; ++mt) {
      float sum = 0.f;
      if (hasMask) {
        // lane covers q = qbase+16mt+fm, keys it*64 + 16kt + 4q4 + r -> uint32 per kt
        const unsigned char* mrow = mask + mbase + (size_t)(qbase + mt * 16 + fm) * LQ + it * 64 + q4 * 4;
#pragma unroll
        for (int kt = 0; kt < 4; ++kt) {
          const uint32_t mv = *(const uint32_t*)(mrow + kt * 16);
#pragma unroll
          for (int r = 0; r < 4; ++r) {
            float e = ((mv >> (8 * r)) & 0xffu) ? 0.f : exp2f(st[kt][mt][r] * SCALE_LOG2E);
            st[kt][mt][r] = e;
            sum += e;
          }
        }
      } else {
#pragma unroll
        for (int kt = 0; kt < 4; ++kt)
#pragma unroll
          for (int r = 0; r < 4; ++r) {
            float e = exp2f(st[kt][mt][r] * SCALE_LOG2E);
            st[kt][mt][r] = e;
            sum += e;
          }
      }
      // row-sum for q=16mt+fm: 16 local + combine the 4 q4 groups
      sum += __shfl_xor(sum, 16);
      sum += __shfl_xor(sum, 32);
      lsumv[mt] += sum;
      // pack P pairs: pk[mt][kt][h] = bf16{st[2h], st[2h+1]} (keys 16kt+4q4+2h,+1)
#pragma unroll
      for (int kt = 0; kt < 4; ++kt) {
        pk[mt][kt][0] = cvtpk(st[kt][mt][0], st[kt][mt][1]);
        pk[mt][kt][1] = cvtpk(st[kt][mt][2], st[kt][mt][3]);
      }
    }

    // ---- O += P V  (P A-frags built in-register via bpermute exchange)
#pragma unroll
    for (int ns = 0; ns < 2; ++ns) {
      bf16x8 paf[2];
#pragma unroll
      for (int mt = 0; mt < 2; ++mt) {
        uint32_t t0, t1, t2, t3, u0, u1, u2, u3;
        bperm8(t0, t1, t2, t3, u0, u1, u2, u3, al, ah,
               pk[mt][2 * ns][0], pk[mt][2 * ns][1],
               pk[mt][2 * ns + 1][0], pk[mt][2 * ns + 1][1]);
        union { uint32_t u[4]; bf16x8 v; } fb;
        fb.u[0] = sel_hi ? u0 : t0;   // keys 8q4+{0,1}
        fb.u[1] = sel_hi ? u1 : t1;   // keys 8q4+{2,3}
        fb.u[2] = sel_hi ? u2 : t2;   // keys 8q4+{4,5}
        fb.u[3] = sel_hi ? u3 : t3;   // keys 8q4+{6,7}
        paf[mt] = fb.v;
      }
      const int vslot = (4 * ns + q4) ^ f7;
      bf16x8 v0, v1, v2, v3, v4, v5, v6, v7;
      ldsr4(v0, v1, v2, v3,
            lds_b(VT + (0 * 16 + fm) * 64 + vslot * 8), lds_b(VT + (1 * 16 + fm) * 64 + vslot * 8),
            lds_b(VT + (2 * 16 + fm) * 64 + vslot * 8), lds_b(VT + (3 * 16 + fm) * 64 + vslot * 8));
      ldsr4(v4, v5, v6, v7,
            lds_b(VT + (4 * 16 + fm) * 64 + vslot * 8), lds_b(VT + (5 * 16 + fm) * 64 + vslot * 8),
            lds_b(VT + (6 * 16 + fm) * 64 + vslot * 8), lds_b(VT + (7 * 16 + fm) * 64 + vslot * 8));
      o[0][0] = __builtin_amdgcn_mfma_f32_16x16x32_bf16(paf[0], v0, o[0][0], 0, 0, 0);
      o[1][0] = __builtin_amdgcn_mfma_f32_16x16x32_bf16(paf[1], v0, o[1][0], 0, 0, 0);
      o[0][1] = __builtin_amdgcn_mfma_f32_16x16x32_bf16(paf[0], v1, o[0][1], 0, 0, 0);
      o[1][1] = __builtin_amdgcn_mfma_f32_16x16x32_bf16(paf[1], v1, o[1][1], 0, 0, 0);
      o[0][2] = __builtin_amdgcn_mfma_f32_16x16x32_bf16(paf[0], v2, o[0][2], 0, 0, 0);
      o[1][2] = __builtin_amdgcn_mfma_f32_16x16x32_bf16(paf[1], v2, o[1][2], 0, 0, 0);
      o[0][3] = __builtin_amdgcn_mfma_f32_16x16x32_bf16(paf[0], v3, o[0][3], 0, 0, 0);
      o[1][3] = __builtin_amdgcn_mfma_f32_16x16x32_bf16(paf[1], v3, o[1][3], 0, 0, 0);
      o[0][4] = __builtin_amdgcn_mfma_f32_16x16x32_bf16(paf[0], v4, o[0][4], 0, 0, 0);
      o[1][4] = __builtin_amdgcn_mfma_f32_16x16x32_bf16(paf[1], v4, o[1][4], 0, 0, 0);
      o[0][5] = __builtin_amdgcn_mfma_f32_16x16x32_bf16(paf[0], v5, o[0][5], 0, 0, 0);
      o[1][5] = __builtin_amdgcn_mfma_f32_16x16x32_bf16(paf[1], v5, o[1][5], 0, 0, 0);
      o[0][6] = __builtin_amdgcn_mfma_f32_16x16x32_bf16(paf[0], v6, o[0][6], 0, 0, 0);
      o[1][6] = __builtin_amdgcn_mfma_f32_16x16x32_bf16(paf[1], v6, o[1][6], 0, 0, 0);
      o[0][7] = __builtin_amdgcn_mfma_f32_16x16x32_bf16(paf[0], v7, o[0][7], 0, 0, 0);
      o[1][7] = __builtin_amdgcn_mfma_f32_16x16x32_bf16(paf[1], v7, o[1][7], 0, 0, 0);
    }
  }

  // ---- epilogue: ctx = O / lsum. lsum for q=16mt+(q4*4+r) lives on lane fm'=q4*4+r (q4'=0).
#pragma unroll
  for (int mt = 0; mt < 2; ++mt)
#pragma unroll
    for (int r = 0; r < 4; ++r) {
      float inv = 1.f / __shfl(lsumv[mt], q4 * 4 + r);
      int gq = b * LQ + qbase + mt * 16 + q4 * 4 + r;
#pragma unroll
      for (int dt = 0; dt < 8; ++dt)
        ctx[(size_t)gq * EDIM + h * DH + dt * 16 + fm] = f2bf(o[mt][dt][r] * inv);
    }
}

extern "C" void kernel_launch(void* const* d_in, const int* in_sizes, int n_in,
                              void* d_out, int out_size, void* d_ws, size_t ws_size,
                              hipStream_t stream) {
  const float* qIn = (const float*)d_in[0];
  const float* kvIn = (const float*)d_in[1];
  const unsigned char* mask = (const unsigned char*)d_in[2];
  const float* W_Q = (const float*)d_in[3];
  const float* W_K = (const float*)d_in[4];
  const float* W_V = (const float*)d_in[5];
  const float* W_fc = (const float*)d_in[6];
  float* out = (float*)d_out;

  uint8_t* ws = (uint8_t*)d_ws;
  const size_t MB = 1u << 20;
  u16* xq   = (u16*)(ws);
  u16* xkv  = (u16*)(ws + 16 * MB);
  u16* WqT  = (u16*)(ws + 32 * MB);
  u16* WkT  = (u16*)(ws + 34 * MB);
  u16* WvT  = (u16*)(ws + 36 * MB);
  u16* WfcT = (u16*)(ws + 38 * MB);
  u16* Qb   = (u16*)(ws + 40 * MB);
  u16* Kb   = (u16*)(ws + 56 * MB);
  u16* Vt   = (u16*)(ws + 72 * MB);
  u16* ctx  = (u16*)(ws + 88 * MB);
  unsigned char* flags = (unsigned char*)(ws + 104 * MB);

  prep_kernel<<<20480, 256, 0, stream>>>(qIn, kvIn, W_Q, W_K, W_V, W_fc,
                                         xq, xkv, WqT, WkT, WvT, WfcT);
  qkv_gemm<<<dim3(64, 8, 4), 256, 0, stream>>>(xq, xkv, WqT, WkT, WvT, Qb, Kb, Vt, mask, flags);
  attn_kernel<<<dim3(16, 8, 4), 256, 0, stream>>>(Qb, Kb, Vt, mask, flags, ctx);
  out_gemm<<<dim3(64, 8), 256, 0, stream>>>(ctx, WfcT, out);
}